// Round 4
// baseline (347.550 us; speedup 1.0000x reference)
//
#include <hip/hip_runtime.h>
#include <hip/hip_bf16.h>
#include <math.h>

#define H 120
#define W 216
#define C 256
#define NPIX (H*W)
#define PATCH 13
#define PP 169
#define RAD 6
#define TOPKN 36
#define OBJ 11
#define MD 4
#define CW 344   // padded corr row stride (338 -> 344)

// ---------------- kernel 1: mask downsample (::4,::4) ----------------
__global__ void k_downsample(const float* __restrict__ m0, const float* __restrict__ m1,
                             float* __restrict__ mds) {
  int i = blockIdx.x * 256 + threadIdx.x;
  const int total = 2 * OBJ * NPIX;
  if (i >= total) return;
  int fo = i / NPIX;
  int pix = i - fo * NPIX;
  int f = fo / OBJ, o = fo - f * OBJ;
  int y = pix / W, x = pix - y * W;
  const float* src = f ? m1 : m0;
  mds[i] = src[(size_t)o * (H*MD) * (W*MD) + (size_t)(MD*y) * (W*MD) + MD*x];
}

// ---------------- kernel 2: local correlation ----------------
// block = 256 threads = 4 waves, one (y, di, f) slice per block.
// wave w handles channels [w*64, w*64+64) in 16 chunks of 4; partials tree-reduced in LDS.
// Main loop: NO barriers (per-wave private LDS region), register-prefetched staging.
__global__ __launch_bounds__(256, 4) void k_corr(const float* __restrict__ fq,
                       const float* __restrict__ fm0, const float* __restrict__ fm1,
                       float* __restrict__ corr) {
  // XCD-aware swizzle: 3120 = 8 * 390; contiguous y-range per XCD.
  int b = blockIdx.x;
  int lb = (b & 7) * 390 + (b >> 3);
  int y   = lb / 26;
  int r26 = lb - y * 26;
  int f   = r26 / 13;
  int di  = r26 - f * 13;
  const int tid  = threadIdx.x;
  const int wv   = tid >> 6;
  const int lane = tid & 63;
  const int xg   = lane;          // xg < 54 active for compute
  const int r    = y + di - RAD;  // fm source row
  const bool rowok = (r >= 0) && (r < H);

  // fm regions: wave w at smem[w*928 .. +928). reduce regions r0=smem[0..3328), r1=smem[3328..6656)
  __shared__ float smem[6656];
  float* fm_s = smem + wv * 928;

  const float* fm = f ? fm1 : fm0;

  // staging slots: 232 float4 slots per chunk ([4 ch][58 f4]), this wave's lane handles
  // slots lane, lane+64, lane+128, lane+192
  const float* pf[4];
  int  ldsoff[4];
  bool sval[4], mval[4];
  #pragma unroll
  for (int s = 0; s < 4; ++s) {
    int i = lane + 64 * s;
    sval[s] = (i < 232);
    int ii = sval[s] ? i : 0;
    int ch = ii / 58;
    int m  = ii - ch * 58;
    int x  = 4 * m - 8;
    mval[s] = sval[s] && (m >= 2) && (m <= 55) && rowok;
    ldsoff[s] = ch * 232 + 4 * m;
    pf[s] = fm + (size_t)(wv * 64 + ch) * NPIX + (size_t)(rowok ? r : 0) * W + (mval[s] ? x : 0);
  }

  const float* pq = fq + (size_t)(wv * 64) * NPIX + (size_t)y * W + 4 * ((xg < 54) ? xg : 0);

  float4 acc[PATCH];
  #pragma unroll
  for (int d = 0; d < PATCH; ++d) acc[d] = make_float4(0.f, 0.f, 0.f, 0.f);

  if (rowok) {
    // prologue: prefetch chunk 0
    float4 pre[4];
    #pragma unroll
    for (int s = 0; s < 4; ++s) {
      pre[s] = make_float4(0.f, 0.f, 0.f, 0.f);
      if (mval[s]) pre[s] = *(const float4*)(pf[s]);
      pf[s] += 4 * (size_t)NPIX;
    }

    for (int chunk = 0; chunk < 16; ++chunk) {
      // stage prefetched chunk to this wave's private LDS region
      #pragma unroll
      for (int s = 0; s < 4; ++s) {
        if (sval[s]) *(float4*)&fm_s[ldsoff[s]] = pre[s];
      }
      // issue next chunk's global loads (land during compute below)
      if (chunk < 15) {
        #pragma unroll
        for (int s = 0; s < 4; ++s) {
          pre[s] = make_float4(0.f, 0.f, 0.f, 0.f);
          if (mval[s]) pre[s] = *(const float4*)(pf[s]);
          pf[s] += 4 * (size_t)NPIX;
        }
      }
      __builtin_amdgcn_wave_barrier();  // keep ds_write/ds_read ordering; no code emitted

      if (xg < 54) {
        #pragma unroll
        for (int ch = 0; ch < 4; ++ch) {
          float4 q4 = *(const float4*)(pq + (size_t)ch * NPIX);
          float rr[20];
          #pragma unroll
          for (int q = 0; q < 5; ++q) {
            float4 t4 = *(const float4*)&fm_s[ch * 232 + 4 * xg + 4 * q];
            rr[4*q+0] = t4.x; rr[4*q+1] = t4.y; rr[4*q+2] = t4.z; rr[4*q+3] = t4.w;
          }
          #pragma unroll
          for (int dj = 0; dj < PATCH; ++dj) {
            acc[dj].x += q4.x * rr[dj + 2];
            acc[dj].y += q4.y * rr[dj + 3];
            acc[dj].z += q4.z * rr[dj + 4];
            acc[dj].w += q4.w * rr[dj + 5];
          }
        }
        pq += 4 * (size_t)NPIX;
      }
      __builtin_amdgcn_wave_barrier();
    }
  }

  // ---- cross-wave reduce: final = (S0+S1) + (S2+S3) ----
  float* af = reinterpret_cast<float*>(acc);
  float* r0 = smem;
  float* r1 = smem + 3328;

  __syncthreads();
  if (wv == 1) {
    #pragma unroll
    for (int j = 0; j < 52; ++j) r0[j * 64 + lane] = af[j];
  }
  if (wv == 3) {
    #pragma unroll
    for (int j = 0; j < 52; ++j) r1[j * 64 + lane] = af[j];
  }
  __syncthreads();
  if (wv == 0) {
    #pragma unroll
    for (int j = 0; j < 52; ++j) af[j] += r0[j * 64 + lane];
  }
  if (wv == 2) {
    #pragma unroll
    for (int j = 0; j < 52; ++j) af[j] += r1[j * 64 + lane];
  }
  __syncthreads();
  if (wv == 2) {
    #pragma unroll
    for (int j = 0; j < 52; ++j) r0[j * 64 + lane] = af[j];
  }
  __syncthreads();

  if (wv == 0 && xg < 54) {
    #pragma unroll
    for (int j = 0; j < 52; ++j) af[j] += r0[j * 64 + lane];
    float* cp = corr + (size_t)(y * W) * CW + (f * PP + di * PATCH) + (size_t)(4 * xg) * CW;
    #pragma unroll
    for (int dj = 0; dj < PATCH; ++dj) {
      cp[dj]                  = acc[dj].x * 0.0625f;
      cp[(size_t)1 * CW + dj] = acc[dj].y * 0.0625f;
      cp[(size_t)2 * CW + dj] = acc[dj].z * 0.0625f;
      cp[(size_t)3 * CW + dj] = acc[dj].w * 0.0625f;
    }
  }
}

// ---------------- kernel 3: per-pixel top-36 + softmax + mask gather ----------------
// one wave (64 lanes) per pixel  (unchanged — validated)
__global__ __launch_bounds__(256) void k_topk(const float* __restrict__ corr,
                       const float* __restrict__ mds, float* __restrict__ out) {
  int wid = (blockIdx.x * 256 + threadIdx.x) >> 6;
  int lane = threadIdx.x & 63;
  if (wid >= NPIX) return;
  const float* cr = corr + (size_t)wid * CW;

  float v[6];
  #pragma unroll
  for (int s = 0; s < 6; ++s) {
    int idx = lane + 64 * s;
    v[s] = (idx < 2 * PP) ? cr[idx] : -INFINITY;
  }

  float m = 0.f, sum = 0.f, my_w = 0.f;
  int my_idx = 0;
  for (int k = 0; k < TOPKN; ++k) {
    float bv = v[0]; int bs = 0;
    #pragma unroll
    for (int q = 1; q < 6; ++q) { if (v[q] > bv) { bv = v[q]; bs = q; } }
    int bidx = lane + 64 * bs;
    #pragma unroll
    for (int off = 32; off >= 1; off >>= 1) {
      float ov = __shfl_xor(bv, off, 64);
      int   oi = __shfl_xor(bidx, off, 64);
      if (ov > bv || (ov == bv && oi < bidx)) { bv = ov; bidx = oi; }
    }
    if (k == 0) m = bv;
    float wv = __expf(bv - m);
    sum += wv;
    if (lane == k) { my_w = wv; my_idx = bidx; }
    if ((bidx & 63) == lane) {
      int s = bidx >> 6;
      #pragma unroll
      for (int q = 0; q < 6; ++q) { if (s == q) v[q] = -INFINITY; }
    }
  }

  int y = wid / W, x = wid - (wid / W) * W;
  float part[OBJ];
  #pragma unroll
  for (int o = 0; o < OBJ; ++o) part[o] = 0.f;
  if (lane < TOPKN) {
    int idx = my_idx;
    int f = (idx >= PP) ? 1 : 0;
    int rr = idx - f * PP;
    int di = rr / PATCH, dj = rr - (rr / PATCH) * PATCH;
    int yy = y + di - RAD, xx = x + dj - RAD;
    if (yy >= 0 && yy < H && xx >= 0 && xx < W) {
      const float* mb = mds + ((size_t)f * OBJ) * NPIX + yy * W + xx;
      #pragma unroll
      for (int o = 0; o < OBJ; ++o) part[o] = my_w * mb[(size_t)o * NPIX];
    }
  }
  float inv = 1.f / sum;
  #pragma unroll
  for (int o = 0; o < OBJ; ++o) {
    float p = part[o];
    #pragma unroll
    for (int off = 32; off >= 1; off >>= 1) p += __shfl_xor(p, off, 64);
    if (lane == 0) out[(size_t)o * NPIX + wid] = p * inv;
  }
}

extern "C" void kernel_launch(void* const* d_in, const int* in_sizes, int n_in,
                              void* d_out, int out_size, void* d_ws, size_t ws_size,
                              hipStream_t stream) {
  const float* fq  = (const float*)d_in[0];
  const float* fm0 = (const float*)d_in[1];
  const float* fm1 = (const float*)d_in[2];
  const float* m0  = (const float*)d_in[3];
  const float* m1  = (const float*)d_in[4];
  float* out = (float*)d_out;

  char* ws = (char*)d_ws;
  float* mds  = (float*)ws;
  size_t mds_bytes = (size_t)2 * OBJ * NPIX * sizeof(float);
  float* corr = (float*)(ws + ((mds_bytes + 1023) / 1024) * 1024);

  k_downsample<<<(2 * OBJ * NPIX + 255) / 256, 256, 0, stream>>>(m0, m1, mds);

  k_corr<<<120 * 26, 256, 0, stream>>>(fq, fm0, fm1, corr);

  k_topk<<<NPIX / 4, 256, 0, stream>>>(corr, mds, out);
}

// Round 5
// 341.390 us; speedup vs baseline: 1.0180x; 1.0180x over previous
//
#include <hip/hip_runtime.h>
#include <hip/hip_bf16.h>
#include <math.h>

#define H 120
#define W 216
#define C 256
#define NPIX (H*W)
#define PATCH 13
#define PP 169
#define RAD 6
#define TOPKN 36
#define OBJ 11
#define MD 4
#define CW 344   // padded corr row stride (338 -> 344)

typedef unsigned short ushort;
typedef unsigned int   uint;
typedef __attribute__((ext_vector_type(8))) __bf16 bf16x8;
typedef __attribute__((ext_vector_type(4))) float   f32x4;

#define PLANE_B ((size_t)NPIX * 512)   // bytes per hi/lo plane of a transposed tensor

__device__ inline ushort f2bf_rne(float x) {
  uint u = __float_as_uint(x);
  uint r = (u + 0x7FFFu + ((u >> 16) & 1u)) >> 16;
  return (ushort)r;
}
__device__ inline float bf2f(ushort h) { return __uint_as_float(((uint)h) << 16); }

// ---------------- kernel 0: transpose + hi/lo bf16 split ----------------
// grid (405 pix-chunks, 4 c-quarters, 3 tensors), block 256.
// out layout per tensor: [2 planes][NPIX][256] bf16 (hi plane then lo plane).
__global__ __launch_bounds__(256) void k_prep(const float* __restrict__ fq,
                      const float* __restrict__ fm0, const float* __restrict__ fm1,
                      char* fqt, char* fm0t, char* fm1t) {
  const float* src = (blockIdx.z == 0) ? fq : (blockIdx.z == 1) ? fm0 : fm1;
  char* dst = (blockIdx.z == 0) ? fqt : (blockIdx.z == 1) ? fm0t : fm1t;

  const int p0 = blockIdx.x * 64;
  const int c0 = blockIdx.y * 64;
  const int tid = threadIdx.x;

  __shared__ float ts[64 * 65];
  // phase 1: read [64 c][64 p] f32, coalesced
  {
    int p = tid & 63, cl = tid >> 6;
    #pragma unroll
    for (int jj = 0; jj < 16; ++jj) {
      int c = 4 * jj + cl;
      ts[c * 65 + p] = src[(size_t)(c0 + c) * NPIX + p0 + p];
    }
  }
  __syncthreads();
  // phase 2: write [p][c] bf16 hi/lo, coalesced 32B per thread per plane
  {
    int pl = tid >> 2, sub = tid & 3;
    ushort hb[16], lb[16];
    #pragma unroll
    for (int i = 0; i < 16; ++i) {
      float x = ts[(sub * 16 + i) * 65 + pl];
      ushort h = f2bf_rne(x);
      hb[i] = h;
      lb[i] = f2bf_rne(x - bf2f(h));
    }
    size_t off = (size_t)(p0 + pl) * 512 + (size_t)c0 * 2 + sub * 32;
    *(uint4*)(dst + off)            = ((uint4*)hb)[0];
    *(uint4*)(dst + off + 16)       = ((uint4*)hb)[1];
    *(uint4*)(dst + PLANE_B + off)      = ((uint4*)lb)[0];
    *(uint4*)(dst + PLANE_B + off + 16) = ((uint4*)lb)[1];
  }
}

// ---------------- kernel 1: mask downsample (::4,::4) ----------------
__global__ void k_downsample(const float* __restrict__ m0, const float* __restrict__ m1,
                             float* __restrict__ mds) {
  int i = blockIdx.x * 256 + threadIdx.x;
  const int total = 2 * OBJ * NPIX;
  if (i >= total) return;
  int fo = i / NPIX;
  int pix = i - fo * NPIX;
  int f = fo / OBJ, o = fo - f * OBJ;
  int y = pix / W, x = pix - y * W;
  const float* src = f ? m1 : m0;
  mds[i] = src[(size_t)o * (H*MD) * (W*MD) + (size_t)(MD*y) * (W*MD) + MD*x];
}

// ---------------- kernel 2 (MFMA): local correlation, one (y,di,f) slice per block ----------------
// 4 waves; wave w owns x in [64w, 64w+64) = 4 M-tiles of 16. Per K-chunk (32 ch):
// B (fm row r, ui = u+8 in [0,232)) staged to LDS [2 planes][240 rows][40 bf16] (80B stride);
// A (fq) fragments loaded straight from global [pix][256] hi/lo planes.
// S[x][u] accumulated fp32 via 3 MFMAs (ah*bh + ah*bl + al*bh); band-extract dj at store.
__global__ __launch_bounds__(256, 3) void k_corr_mfma(const char* __restrict__ fqt,
                        const char* __restrict__ fm0t, const char* __restrict__ fm1t,
                        float* __restrict__ corr) {
  int b = blockIdx.x;
  int lb = (b & 7) * 390 + (b >> 3);
  int y   = lb / 26;
  int r26 = lb - y * 26;
  int f   = r26 / 13;
  int di  = r26 - f * 13;
  const int tid  = threadIdx.x;
  const int w    = tid >> 6;
  const int lane = tid & 63;
  const int rr   = y + di - RAD;

  float* cbase = corr + (size_t)(y * W) * CW + (f * PP + di * PATCH);

  if (rr < 0 || rr >= H) {
    for (int i = tid; i < W * PATCH; i += 256) {
      int x = i / PATCH, dj = i - (i / PATCH) * PATCH;
      cbase[(size_t)x * CW + dj] = 0.f;
    }
    return;
  }

  const char* frame = f ? fm1t : fm0t;

  __shared__ __align__(16) ushort bsm[2 * 240 * 40];   // 38400 B

  // ---- precompute staging slots: 1856 granules = [2 planes][232 px][4 quarters] x 16B
  uint soff[8];   // source byte offset within frame (sans kc*64); 0xFFFFFFFF => zero-fill
  uint ldso[8];   // LDS ushort offset
  #pragma unroll
  for (int s = 0; s < 8; ++s) {
    int gid = tid + 256 * s;
    bool val = (gid < 1856);
    int g  = val ? gid : 0;
    int pi = g / 928;
    int rem = g - pi * 928;
    int px = rem >> 2, q = rem & 3;
    int u  = px - 8;
    bool uok = val && (u >= 0) && (u < W);
    ldso[s] = pi * 9600 + px * 40 + q * 8;
    soff[s] = uok ? (uint)((size_t)pi * PLANE_B + (size_t)(rr * W + u) * 512 + q * 16)
                  : 0xFFFFFFFFu;
    if (!val) ldso[s] = 0xFFFFFFFFu;
  }

  const int l15 = lane & 15, l4 = lane >> 4;

  f32x4 acc[4][2];
  #pragma unroll
  for (int tt = 0; tt < 4; ++tt) {
    acc[tt][0] = (f32x4){0.f, 0.f, 0.f, 0.f};
    acc[tt][1] = (f32x4){0.f, 0.f, 0.f, 0.f};
  }

  // A pixel base addrs (clamped for x>=W; those outputs are discarded)
  const char* abase[4];
  #pragma unroll
  for (int tt = 0; tt < 4; ++tt) {
    int x = 64 * w + 16 * tt + l15;
    int pix = y * W + ((x < W) ? x : 0);
    abase[tt] = fqt + (size_t)pix * 512 + l4 * 16;
  }

  for (int kc = 0; kc < 8; ++kc) {
    // ---- stage B chunk ----
    #pragma unroll
    for (int s = 0; s < 8; ++s) {
      if (ldso[s] != 0xFFFFFFFFu) {
        uint4 v = make_uint4(0, 0, 0, 0);
        if (soff[s] != 0xFFFFFFFFu)
          v = *(const uint4*)(frame + (size_t)soff[s] + kc * 64);
        *(uint4*)&bsm[ldso[s]] = v;
      }
    }
    __syncthreads();

    // ---- A fragments (global, L1/L2-cached) ----
    bf16x8 Ah[4], Al[4];
    #pragma unroll
    for (int tt = 0; tt < 4; ++tt) {
      const char* pa = abase[tt] + kc * 64;
      Ah[tt] = *(const bf16x8*)(pa);
      Al[tt] = *(const bf16x8*)(pa + PLANE_B);
    }
    // ---- B fragments (LDS) ----
    bf16x8 Bh[5], Bl[5];
    #pragma unroll
    for (int g = 0; g < 5; ++g) {
      int ui = 64 * w + 16 * g + l15;
      const ushort* pb = &bsm[ui * 40 + l4 * 8];
      Bh[g] = *(const bf16x8*)pb;
      Bl[g] = *(const bf16x8*)(pb + 9600);
    }
    // ---- 24 MFMAs ----
    #pragma unroll
    for (int tt = 0; tt < 4; ++tt) {
      #pragma unroll
      for (int nt = 0; nt < 2; ++nt) {
        int g = tt + nt;
        acc[tt][nt] = __builtin_amdgcn_mfma_f32_16x16x32_bf16(Ah[tt], Bh[g], acc[tt][nt], 0, 0, 0);
        acc[tt][nt] = __builtin_amdgcn_mfma_f32_16x16x32_bf16(Ah[tt], Bl[g], acc[tt][nt], 0, 0, 0);
        acc[tt][nt] = __builtin_amdgcn_mfma_f32_16x16x32_bf16(Al[tt], Bh[g], acc[tt][nt], 0, 0, 0);
      }
    }
    __syncthreads();
  }

  // ---- band extraction: D[m][n] -> corr[x][dj], dj = 16*nt + n - m - 2 ----
  #pragma unroll
  for (int tt = 0; tt < 4; ++tt) {
    #pragma unroll
    for (int nt = 0; nt < 2; ++nt) {
      #pragma unroll
      for (int j = 0; j < 4; ++j) {
        int m = l4 * 4 + j;
        int x = 64 * w + 16 * tt + m;
        int dj = 16 * nt + l15 - m - 2;
        if (x < W && dj >= 0 && dj < PATCH)
          cbase[(size_t)x * CW + dj] = acc[tt][nt][j] * 0.0625f;
      }
    }
  }
}

// ---------------- kernel 2 fallback (VALU, R2-validated) ----------------
__global__ __launch_bounds__(64) void k_corr_valu(const float* __restrict__ fq,
                       const float* __restrict__ fm0, const float* __restrict__ fm1,
                       float* __restrict__ corr) {
  int b = blockIdx.x;
  int lb = (b & 7) * 390 + (b >> 3);
  int y   = lb / 26;
  int r26 = lb - y * 26;
  int f   = r26 / 13;
  int di  = r26 - f * 13;
  const int tid = threadIdx.x;
  const int xg  = tid;
  const int r   = y + di - RAD;

  float* corr_base = corr + (size_t)(y * W) * CW + (f * PP + di * PATCH);

  if (r < 0 || r >= H) {
    if (xg < 54) {
      float* cp = corr_base + (size_t)(4 * xg) * CW;
      #pragma unroll
      for (int sub = 0; sub < 4; ++sub) {
        #pragma unroll
        for (int dj = 0; dj < PATCH; ++dj) cp[(size_t)sub * CW + dj] = 0.f;
      }
    }
    return;
  }

  const float* fm = f ? fm1 : fm0;
  __shared__ float fm_s[4 * 232];

  const float* pf[4];
  int  ldsoff[4];
  bool sval[4], mval[4];
  #pragma unroll
  for (int s = 0; s < 4; ++s) {
    int i = tid + 64 * s;
    sval[s] = (i < 232);
    int ii = sval[s] ? i : 0;
    int ch = ii / 58;
    int m  = ii - ch * 58;
    int x  = 4 * m - 8;
    mval[s] = sval[s] && (m >= 2) && (m <= 55);
    ldsoff[s] = ch * 232 + 4 * m;
    pf[s] = fm + (size_t)ch * NPIX + (size_t)r * W + (mval[s] ? x : 0);
  }

  const float* pq = fq + (size_t)y * W + 4 * ((xg < 54) ? xg : 0);

  float4 acc[PATCH];
  #pragma unroll
  for (int d = 0; d < PATCH; ++d) acc[d] = make_float4(0.f, 0.f, 0.f, 0.f);

  for (int c0 = 0; c0 < C; c0 += 4) {
    #pragma unroll
    for (int s = 0; s < 4; ++s) {
      if (sval[s]) {
        float4 v = make_float4(0.f, 0.f, 0.f, 0.f);
        if (mval[s]) v = *(const float4*)(pf[s]);
        *(float4*)&fm_s[ldsoff[s]] = v;
        pf[s] += 4 * (size_t)NPIX;
      }
    }
    __syncthreads();
    if (xg < 54) {
      #pragma unroll
      for (int ch = 0; ch < 4; ++ch) {
        float4 q4 = *(const float4*)(pq + (size_t)ch * NPIX);
        float rv[20];
        #pragma unroll
        for (int q = 0; q < 5; ++q) {
          float4 t4 = *(const float4*)&fm_s[ch * 232 + 4 * xg + 4 * q];
          rv[4*q+0] = t4.x; rv[4*q+1] = t4.y; rv[4*q+2] = t4.z; rv[4*q+3] = t4.w;
        }
        #pragma unroll
        for (int dj = 0; dj < PATCH; ++dj) {
          acc[dj].x += q4.x * rv[dj + 2];
          acc[dj].y += q4.y * rv[dj + 3];
          acc[dj].z += q4.z * rv[dj + 4];
          acc[dj].w += q4.w * rv[dj + 5];
        }
      }
      pq += 4 * (size_t)NPIX;
    }
    __syncthreads();
  }

  if (xg < 54) {
    float* cp = corr_base + (size_t)(4 * xg) * CW;
    #pragma unroll
    for (int dj = 0; dj < PATCH; ++dj) {
      cp[dj]                  = acc[dj].x * 0.0625f;
      cp[(size_t)1 * CW + dj] = acc[dj].y * 0.0625f;
      cp[(size_t)2 * CW + dj] = acc[dj].z * 0.0625f;
      cp[(size_t)3 * CW + dj] = acc[dj].w * 0.0625f;
    }
  }
}

// ---------------- kernel 3: per-pixel top-36 + softmax + mask gather ----------------
__global__ __launch_bounds__(256) void k_topk(const float* __restrict__ corr,
                       const float* __restrict__ mds, float* __restrict__ out) {
  int wid = (blockIdx.x * 256 + threadIdx.x) >> 6;
  int lane = threadIdx.x & 63;
  if (wid >= NPIX) return;
  const float* cr = corr + (size_t)wid * CW;

  float v[6];
  #pragma unroll
  for (int s = 0; s < 6; ++s) {
    int idx = lane + 64 * s;
    v[s] = (idx < 2 * PP) ? cr[idx] : -INFINITY;
  }

  float m = 0.f, sum = 0.f, my_w = 0.f;
  int my_idx = 0;
  for (int k = 0; k < TOPKN; ++k) {
    float bv = v[0]; int bs = 0;
    #pragma unroll
    for (int q = 1; q < 6; ++q) { if (v[q] > bv) { bv = v[q]; bs = q; } }
    int bidx = lane + 64 * bs;
    #pragma unroll
    for (int off = 32; off >= 1; off >>= 1) {
      float ov = __shfl_xor(bv, off, 64);
      int   oi = __shfl_xor(bidx, off, 64);
      if (ov > bv || (ov == bv && oi < bidx)) { bv = ov; bidx = oi; }
    }
    if (k == 0) m = bv;
    float wv = __expf(bv - m);
    sum += wv;
    if (lane == k) { my_w = wv; my_idx = bidx; }
    if ((bidx & 63) == lane) {
      int s = bidx >> 6;
      #pragma unroll
      for (int q = 0; q < 6; ++q) { if (s == q) v[q] = -INFINITY; }
    }
  }

  int y = wid / W, x = wid - (wid / W) * W;
  float part[OBJ];
  #pragma unroll
  for (int o = 0; o < OBJ; ++o) part[o] = 0.f;
  if (lane < TOPKN) {
    int idx = my_idx;
    int f = (idx >= PP) ? 1 : 0;
    int rr = idx - f * PP;
    int di = rr / PATCH, dj = rr - (rr / PATCH) * PATCH;
    int yy = y + di - RAD, xx = x + dj - RAD;
    if (yy >= 0 && yy < H && xx >= 0 && xx < W) {
      const float* mb = mds + ((size_t)f * OBJ) * NPIX + yy * W + xx;
      #pragma unroll
      for (int o = 0; o < OBJ; ++o) part[o] = my_w * mb[(size_t)o * NPIX];
    }
  }
  float inv = 1.f / sum;
  #pragma unroll
  for (int o = 0; o < OBJ; ++o) {
    float p = part[o];
    #pragma unroll
    for (int off = 32; off >= 1; off >>= 1) p += __shfl_xor(p, off, 64);
    if (lane == 0) out[(size_t)o * NPIX + wid] = p * inv;
  }
}

extern "C" void kernel_launch(void* const* d_in, const int* in_sizes, int n_in,
                              void* d_out, int out_size, void* d_ws, size_t ws_size,
                              hipStream_t stream) {
  const float* fq  = (const float*)d_in[0];
  const float* fm0 = (const float*)d_in[1];
  const float* fm1 = (const float*)d_in[2];
  const float* m0  = (const float*)d_in[3];
  const float* m1  = (const float*)d_in[4];
  float* out = (float*)d_out;

  char* ws = (char*)d_ws;
  size_t off = 0;
  auto alloc = [&](size_t sz) { size_t o = off; off = (off + sz + 1023) & ~(size_t)1023; return o; };

  size_t mds_o  = alloc((size_t)2 * OBJ * NPIX * sizeof(float));
  size_t corr_o = alloc((size_t)NPIX * CW * sizeof(float));
  size_t fqt_o  = alloc(2 * PLANE_B);
  size_t fm0t_o = alloc(2 * PLANE_B);
  size_t fm1t_o = alloc(2 * PLANE_B);
  size_t needed = off;

  float* mds  = (float*)(ws + mds_o);
  float* corr = (float*)(ws + corr_o);

  k_downsample<<<(2 * OBJ * NPIX + 255) / 256, 256, 0, stream>>>(m0, m1, mds);

  if (ws_size >= needed) {
    char* fqt  = ws + fqt_o;
    char* fm0t = ws + fm0t_o;
    char* fm1t = ws + fm1t_o;
    dim3 gp(405, 4, 3);
    k_prep<<<gp, 256, 0, stream>>>(fq, fm0, fm1, fqt, fm0t, fm1t);
    k_corr_mfma<<<120 * 26, 256, 0, stream>>>(fqt, fm0t, fm1t, corr);
  } else {
    k_corr_valu<<<120 * 26, 64, 0, stream>>>(fq, fm0, fm1, corr);
  }

  k_topk<<<NPIX / 4, 256, 0, stream>>>(corr, mds, out);
}